// Round 1
// baseline (176.282 us; speedup 1.0000x reference)
//
#include <hip/hip_runtime.h>
#include <hip/hip_bf16.h>

#define TD 8
#define TH 8
#define TW 32
#define HD (TD+2)
#define HH (TH+2)
#define HWD (TW+2)
#define HALO_N (HD*HH*HWD)

#define DIM_D 128
#define DIM_H 192
#define DIM_W 192

static __device__ __forceinline__ float sigmoidf(float x) {
    return 1.0f / (1.0f + expf(-x));
}

__global__ __launch_bounds__(256) void lumen_main(
    const float* __restrict__ x_in, const float* __restrict__ y_out,
    const float* __restrict__ y_tg, double* __restrict__ gacc,
    float* __restrict__ dice_i, float* __restrict__ dice_c)
{
    __shared__ float ybs[HD][HH][HWD];
    __shared__ float tgs[HD][HH][HWD];
    __shared__ float dsI[TW], dsC[TW];
    __shared__ float red[4][16];

    const int tid = threadIdx.x;
    const int b  = blockIdx.z >> 4;          // DIM_D/TD = 16 d-tiles
    const int dt = blockIdx.z & 15;
    const int d0 = dt * TD;
    const int h0 = blockIdx.y * TH;
    const int w0 = blockIdx.x * TW;
    const size_t base = (size_t)b * ((size_t)DIM_D * DIM_H * DIM_W);

    if (tid < TW) { dsI[tid] = 0.f; dsC[tid] = 0.f; }

    // ---- halo load: compute yb = sigmoid(200*(sigmoid(y_out)-0.5)) on the fly ----
    for (int l = tid; l < HALO_N; l += 256) {
        int dz = l / (HH*HWD);
        int r  = l - dz*(HH*HWD);
        int dy = r / HWD;
        int dx = r - dy*HWD;
        int gd = d0 - 1 + dz, gh = h0 - 1 + dy, gw = w0 - 1 + dx;
        bool ok = ((unsigned)gd < (unsigned)DIM_D) &&
                  ((unsigned)gh < (unsigned)DIM_H) &&
                  ((unsigned)gw < (unsigned)DIM_W);
        float yb = 0.f, tg = 0.f;
        if (ok) {
            size_t gi = base + ((size_t)gd*DIM_H + gh)*DIM_W + gw;
            float yo = y_out[gi];
            tg = y_tg[gi];
            float yp = sigmoidf(yo);
            yb = sigmoidf((yp - 0.5f)*200.f);
        }
        ((float*)ybs)[l] = yb;
        ((float*)tgs)[l] = tg;
    }
    __syncthreads();

    const int ty = tid >> 5, tx = tid & 31;

    // truncated CDT kernel weights by #nonzero offsets
    const float KC[4]   = {1.0f, 4.5399929762484854e-05f, 7.2135410e-07f, 3.0047e-08f};
    const float LAPW[4] = {-88.f/26.f, 6.f/26.f, 3.f/26.f, 2.f/26.f};
    const float S3[3]   = {47.f/256.f, 162.f/256.f, 47.f/256.f};
    const float DV[3]   = {1.f, 0.f, -1.f};

    float a_ce=0, a_tz=0, a_pzt=0, a_itzi=0, a_ipzti=0, a_yp=0, a_ytg=0;
    float a_y1y2=0, a_y1=0;
    float a_yS1=0, a_ySx=0, a_ySxx=0, a_y4S1=0, a_y4Sx=0, a_y4Sxx=0;
    float dIi=0, dCc=0;

    for (int td = 0; td < TD; ++td) {
        float acx=0, act=0, al=0, a1=0, a2=0, a3=0;
        #pragma unroll
        for (int od=0; od<3; ++od)
        #pragma unroll
        for (int oh=0; oh<3; ++oh)
        #pragma unroll
        for (int ow=0; ow<3; ++ow) {
            float vb = ybs[td+od][ty+oh][tx+ow];
            float vt = tgs[td+od][ty+oh][tx+ow];
            const int c = (od!=1) + (oh!=1) + (ow!=1);
            acx = fmaf(KC[c], vb, acx);
            act = fmaf(KC[c], vt, act);
            al  = fmaf(LAPW[c], vb, al);
            if (ow != 1) a1 = fmaf(S3[od]*S3[oh]*DV[ow], vb, a1);
            if (oh != 1) a2 = fmaf(S3[od]*S3[ow]*DV[oh], vb, a2);
            if (od != 1) a3 = fmaf(S3[oh]*S3[ow]*DV[od], vb, a3);
        }

        float ybc = ybs[td+1][ty+1][tx+1];
        float t   = tgs[td+1][ty+1][tx+1];
        int gd = d0 + td, gh = h0 + ty, gw = w0 + tx;
        size_t gi = base + ((size_t)gd*DIM_H + gh)*DIM_W + gw;
        float yo = y_out[gi];
        float x  = x_in[gi];
        float yp = sigmoidf(yo);

        // CE (stable BCE-with-logits)
        a_ce += fmaxf(yo, 0.f) - yo*t + log1pf(expf(-fabsf(yo)));

        // Dice per-(b,w)
        dIi += yp*t;
        dCc += yp + t;

        // DT: z terms; conv(1-x) = T - conv(x) with boundary-corrected T
        int nd = 2 - (gd==0) - (gd==DIM_D-1);
        int nh = 2 - (gh==0) - (gh==DIM_H-1);
        int nw = 2 - (gw==0) - (gw==DIM_W-1);
        float T = 1.f + KC[1]*(float)(nd+nh+nw)
                      + KC[2]*(float)(nd*nh + nd*nw + nh*nw)
                      + KC[3]*(float)(nd*nh*nw);
        float z    = -0.1f*logf(acx + 1e-6f);
        float ztg  = -0.1f*logf(act + 1e-6f);
        float zinv = -0.1f*logf((T - acx) + 1e-6f);
        float ztgi = -0.1f*logf((T - act) + 1e-6f);
        a_tz    += t*z;
        a_pzt   += yp*ztg;
        a_itzi  += (1.f - t)*zinv;
        a_ipzti += (1.f - yp)*ztgi;
        a_yp    += yp;
        a_ytg   += t;

        // ACE: S-term
        float y1 = sigmoidf((al - 0.5f)*200.f);
        float y2 = sqrtf(a1*a1 + a2*a2 + a3*a3 + 1e-6f);
        a_y1y2 += y1*y2;
        a_y1   += y1;

        // ACE: E-terms (expanded; l1/l2 resolved at finalize)
        float y3 = fmaxf(3.f - z, 0.f);
        float yg = sigmoidf(y3*200.f);
        float y4 = sigmoidf(((3.f - y3)*yg - 0.1f)*200.f);
        a_yS1  += ybc;  a_ySx  += ybc*x;  a_ySxx  += ybc*x*x;
        a_y4S1 += y4;   a_y4Sx += y4*x;   a_y4Sxx += y4*x*x;
    }

    // dice → LDS bins (one bin per w within tile)
    atomicAdd(&dsI[tx], dIi);
    atomicAdd(&dsC[tx], dCc);

    // 15 scalars: wave butterfly reduce, then cross-wave via LDS
    float v[15] = {a_ce, a_tz, a_pzt, a_itzi, a_ipzti, a_yp, a_ytg, a_y1y2, a_y1,
                   a_yS1, a_ySx, a_ySxx, a_y4S1, a_y4Sx, a_y4Sxx};
    #pragma unroll
    for (int k = 0; k < 15; ++k) {
        #pragma unroll
        for (int s = 32; s > 0; s >>= 1) v[k] += __shfl_xor(v[k], s);
    }
    int wid = tid >> 6, lane = tid & 63;
    if (lane == 0) {
        #pragma unroll
        for (int k = 0; k < 15; ++k) red[wid][k] = v[k];
    }
    __syncthreads();
    if (tid < 15) {
        float s = red[0][tid] + red[1][tid] + red[2][tid] + red[3][tid];
        int gidx = (tid < 9) ? tid : (9 + (tid - 9)*2 + b);
        atomicAdd(&gacc[gidx], (double)s);
    }
    if (tid < TW) {
        atomicAdd(&dice_i[b*DIM_W + w0 + tid], dsI[tid]);
        atomicAdd(&dice_c[b*DIM_W + w0 + tid], dsC[tid]);
    }
}

__global__ __launch_bounds__(256) void lumen_final(
    const double* __restrict__ gacc,
    const float* __restrict__ dice_i, const float* __restrict__ dice_c,
    const float* __restrict__ gamma_ace, float* __restrict__ out)
{
    __shared__ float red[4];
    int tid = threadIdx.x;
    float s = 0.f;
    for (int i = tid; i < 2*DIM_W; i += 256) {
        float I = dice_i[i], C = dice_c[i];
        s += 1.f - 2.f*I/(C + 1e-6f);
    }
    #pragma unroll
    for (int sh = 32; sh > 0; sh >>= 1) s += __shfl_xor(s, sh);
    if ((tid & 63) == 0) red[tid >> 6] = s;
    __syncthreads();
    if (tid == 0) {
        double dice_sum = (double)red[0] + red[1] + red[2] + red[3];
        double loss_dice = dice_sum / (2.0*DIM_W);
        const double Nb = (double)DIM_D * DIM_H * DIM_W;
        const double Nt = 2.0 * Nb;
        const double eps = 1e-6;
        double loss_ce = gacc[0]/Nt;
        double dl1 = (gacc[1]/Nt) / ((gacc[6]/Nt) + eps);
        double dl2 = (gacc[2]/Nt) / ((gacc[5]/Nt) + eps);
        double dl3 = (gacc[3]/Nt) / (((Nt - gacc[6])/Nt) + eps);
        double dl4 = (gacc[4]/Nt) / (((Nt - gacc[5])/Nt) + eps);
        double loss_dt = dl1 + dl2 + dl3 + dl4;
        double E1n = 0.0, E2n = 0.0;
        for (int bb = 0; bb < 2; ++bb) {
            double S1 = gacc[9+bb],  Sx = gacc[11+bb], Sxx = gacc[13+bb];
            double l1 = (Sx/Nb) / ((S1/Nb) + eps);
            E1n += Sxx - 2.0*l1*Sx + l1*l1*S1;
            double Q1 = gacc[15+bb], Qx = gacc[17+bb], Qxx = gacc[19+bb];
            double l2 = (Qx/Nb) / ((Q1/Nb) + eps);
            E2n += Qxx - 2.0*l2*Qx + l2*l2*Q1;
        }
        double E1 = (E1n/Nt) / (((gacc[9]+gacc[10])/Nt) + eps);
        double E2 = (E2n/Nt) / (((gacc[15]+gacc[16])/Nt) + eps);
        double S  = (gacc[7]/Nt) / ((gacc[8]/Nt) + eps);
        double loss_ace = E1 + E2 + (double)gamma_ace[0]*S;
        out[0] = (float)(loss_ce + loss_dice + 0.1*loss_dt + 0.1*loss_ace);
    }
}

extern "C" void kernel_launch(void* const* d_in, const int* in_sizes, int n_in,
                              void* d_out, int out_size, void* d_ws, size_t ws_size,
                              hipStream_t stream) {
    const float* x_in  = (const float*)d_in[0];
    const float* y_out = (const float*)d_in[1];
    const float* y_tg  = (const float*)d_in[2];
    const float* gamma = (const float*)d_in[4];
    float* out = (float*)d_out;

    double* gacc  = (double*)d_ws;                       // 21 doubles
    float* dice_i = (float*)((char*)d_ws + 512);         // 384 floats
    float* dice_c = (float*)((char*)d_ws + 2048);        // 384 floats

    hipMemsetAsync(d_ws, 0, 4096, stream);

    dim3 grid(DIM_W/TW, DIM_H/TH, 2*(DIM_D/TD));
    lumen_main<<<grid, 256, 0, stream>>>(x_in, y_out, y_tg, gacc, dice_i, dice_c);
    lumen_final<<<1, 256, 0, stream>>>(gacc, dice_i, dice_c, gamma, out);
}

// Round 2
// 150.683 us; speedup vs baseline: 1.1699x; 1.1699x over previous
//
#include <hip/hip_runtime.h>
#include <hip/hip_bf16.h>

#define TD 8
#define TH 8
#define TW 32
#define HD (TD+2)
#define HH (TH+2)
#define HWD (TW+2)
#define HALO_N (HD*HH*HWD)

#define DIM_D 128
#define DIM_H 192
#define DIM_W 192

__device__ __forceinline__ float frcp(float x) { return __builtin_amdgcn_rcpf(x); }
__device__ __forceinline__ float fsig(float x) { return frcp(1.f + __expf(-x)); }

struct Plane { float u0b, u1b, u2b, s1, s2, s3, u0t, u1t, u2t; };

__device__ __forceinline__ Plane calc_plane(const float ybs[HD][HH][HWD],
                                            const float tgs[HD][HH][HWD],
                                            int dz, int ty, int tx)
{
    const float S30 = 47.f/256.f, S31 = 162.f/256.f;
    float b00=ybs[dz][ty  ][tx], b01=ybs[dz][ty  ][tx+1], b02=ybs[dz][ty  ][tx+2];
    float b10=ybs[dz][ty+1][tx], b11=ybs[dz][ty+1][tx+1], b12=ybs[dz][ty+1][tx+2];
    float b20=ybs[dz][ty+2][tx], b21=ybs[dz][ty+2][tx+1], b22=ybs[dz][ty+2][tx+2];
    Plane P;
    P.u0b = b11;
    P.u1b = (b01 + b21) + (b10 + b12);
    P.u2b = (b00 + b02) + (b20 + b22);
    P.s1  = S30*((b00 - b02) + (b20 - b22)) + S31*(b10 - b12);
    P.s2  = S30*((b00 - b20) + (b02 - b22)) + S31*(b01 - b21);
    P.s3  = (S31*S31)*P.u0b + (S30*S31)*P.u1b + (S30*S30)*P.u2b;
    float t00=tgs[dz][ty  ][tx], t01=tgs[dz][ty  ][tx+1], t02=tgs[dz][ty  ][tx+2];
    float t10=tgs[dz][ty+1][tx], t11=tgs[dz][ty+1][tx+1], t12=tgs[dz][ty+1][tx+2];
    float t20=tgs[dz][ty+2][tx], t21=tgs[dz][ty+2][tx+1], t22=tgs[dz][ty+2][tx+2];
    P.u0t = t11;
    P.u1t = (t01 + t21) + (t10 + t12);
    P.u2t = (t00 + t02) + (t20 + t22);
    return P;
}

__global__ __launch_bounds__(256) void lumen_main(
    const float* __restrict__ x_in, const float* __restrict__ y_out,
    const float* __restrict__ y_tg, double* __restrict__ gacc,
    float* __restrict__ dice_i, float* __restrict__ dice_c)
{
    __shared__ float ybs[HD][HH][HWD];
    __shared__ float tgs[HD][HH][HWD];
    __shared__ float dsI[TW], dsC[TW];
    __shared__ float red[4][16];

    const int tid = threadIdx.x;
    const int b  = blockIdx.z >> 4;
    const int dt = blockIdx.z & 15;
    const int d0 = dt * TD;
    const int h0 = blockIdx.y * TH;
    const int w0 = blockIdx.x * TW;
    const size_t base = (size_t)b * ((size_t)DIM_D * DIM_H * DIM_W);

    if (tid < TW) { dsI[tid] = 0.f; dsC[tid] = 0.f; }

    // ---- halo load: yb = sigmoid(200*(sigmoid(y_out)-0.5)) on the fly ----
    for (int l = tid; l < HALO_N; l += 256) {
        int dz = l / (HH*HWD);
        int r  = l - dz*(HH*HWD);
        int dy = r / HWD;
        int dx = r - dy*HWD;
        int gd = d0 - 1 + dz, gh = h0 - 1 + dy, gw = w0 - 1 + dx;
        bool ok = ((unsigned)gd < (unsigned)DIM_D) &&
                  ((unsigned)gh < (unsigned)DIM_H) &&
                  ((unsigned)gw < (unsigned)DIM_W);
        float yb = 0.f, tg = 0.f;
        if (ok) {
            size_t gi = base + ((size_t)gd*DIM_H + gh)*DIM_W + gw;
            float yo = y_out[gi];
            tg = y_tg[gi];
            float yp = fsig(yo);
            yb = fsig((yp - 0.5f)*200.f);
        }
        ((float*)ybs)[l] = yb;
        ((float*)tgs)[l] = tg;
    }
    __syncthreads();

    const int ty = tid >> 5, tx = tid & 31;
    const int gh = h0 + ty, gw = w0 + tx;

    const float KC1 = 4.5399929762484854e-05f, KC2 = 7.2135410e-07f, KC3 = 3.0047e-08f;
    const float L0 = -88.f/26.f, L1 = 6.f/26.f, L2 = 3.f/26.f, L3 = 2.f/26.f;
    const float S30 = 47.f/256.f, S31 = 162.f/256.f;

    // boundary-corrected total kernel mass, selected per-depth by nd
    const float nh = 2.f - (gh==0) - (gh==DIM_H-1);
    const float nw = 2.f - (gw==0) - (gw==DIM_W-1);
    const float shw = nh + nw, phw = nh * nw;
    const float Tn1 = 1.f + KC1*(1.f+shw) + KC2*(shw+phw) + KC3*phw;
    const float Tn2 = 1.f + KC1*(2.f+shw) + KC2*(2.f*shw+phw) + KC3*(2.f*phw);

    // prefetch the 8 center x / yo values (cold x_in: overlap HBM latency)
    float xr[TD], yor[TD];
    const size_t gbase = base + ((size_t)d0*DIM_H + gh)*DIM_W + gw;
    const size_t dstride = (size_t)DIM_H * DIM_W;
    #pragma unroll
    for (int td = 0; td < TD; ++td) {
        xr[td]  = x_in[gbase + (size_t)td*dstride];
        yor[td] = y_out[gbase + (size_t)td*dstride];
    }

    float a_ce=0, a_tz=0, a_pzt=0, a_itzi=0, a_ipzti=0, a_yp=0, a_ytg=0;
    float a_y1y2=0, a_y1=0;
    float a_yS1=0, a_ySx=0, a_ySxx=0, a_y4S1=0, a_y4Sx=0, a_y4Sxx=0;
    float dIi=0, dCc=0;

    Plane P[3];
    P[0] = calc_plane(ybs, tgs, 0, ty, tx);
    P[1] = calc_plane(ybs, tgs, 1, ty, tx);

    #pragma unroll
    for (int td = 0; td < TD; ++td) {
        P[(td+2)%3] = calc_plane(ybs, tgs, td+2, ty, tx);
        const Plane& A = P[td%3];
        const Plane& B = P[(td+1)%3];
        const Plane& C = P[(td+2)%3];

        const int gd = d0 + td;
        float T = (gd > 0 && gd < DIM_D-1) ? Tn2 : Tn1;

        // cross-plane sums (shared by CDT-x and Laplacian)
        float sb0 = A.u0b + C.u0b, sb1 = A.u1b + C.u1b, sb2 = A.u2b + C.u2b;
        float st0 = A.u0t + C.u0t, st1 = A.u1t + C.u1t, st2 = A.u2t + C.u2t;

        float acx = B.u0b + KC1*(B.u1b + sb0) + KC2*(B.u2b + sb1) + KC3*sb2;
        float act = B.u0t + KC1*(B.u1t + st0) + KC2*(B.u2t + st1) + KC3*st2;
        float al  = L0*B.u0b + L1*(B.u1b + sb0) + L2*(B.u2b + sb1) + L3*sb2;

        float a1 = S30*(A.s1 + C.s1) + S31*B.s1;
        float a2 = S30*(A.s2 + C.s2) + S31*B.s2;
        float a3 = A.s3 - C.s3;

        float ybc = B.u0b;
        float t   = B.u0t;
        float yo  = yor[td];
        float x   = xr[td];
        float yp  = fsig(yo);

        // CE (stable BCE-with-logits)
        a_ce += fmaxf(yo, 0.f) - yo*t + __logf(1.f + __expf(-fabsf(yo)));

        // Dice per-(b,w)
        dIi += yp*t;
        dCc += yp + t;

        // DT terms; conv(1-x) = T - conv(x)
        float z    = -0.1f*__logf(acx + 1e-6f);
        float ztg  = -0.1f*__logf(act + 1e-6f);
        float zinv = -0.1f*__logf((T - acx) + 1e-6f);
        float ztgi = -0.1f*__logf((T - act) + 1e-6f);
        a_tz    += t*z;
        a_pzt   += yp*ztg;
        a_itzi  += (1.f - t)*zinv;
        a_ipzti += (1.f - yp)*ztgi;
        a_yp    += yp;
        a_ytg   += t;

        // ACE S-term
        float y1 = fsig((al - 0.5f)*200.f);
        float y2 = sqrtf(a1*a1 + a2*a2 + a3*a3 + 1e-6f);
        a_y1y2 += y1*y2;
        a_y1   += y1;

        // ACE E-terms. y3 = 3-z (z<=1.382 so relu never clips), yg = sigma(200*y3) = 1
        // exactly in fp32  =>  y4 = sigma(200*z - 20).
        float y4 = fsig(200.f*z - 20.f);
        a_yS1  += ybc;  a_ySx  += ybc*x;  a_ySxx  += ybc*x*x;
        a_y4S1 += y4;   a_y4Sx += y4*x;   a_y4Sxx += y4*x*x;
    }

    atomicAdd(&dsI[tx], dIi);
    atomicAdd(&dsC[tx], dCc);

    float v[15] = {a_ce, a_tz, a_pzt, a_itzi, a_ipzti, a_yp, a_ytg, a_y1y2, a_y1,
                   a_yS1, a_ySx, a_ySxx, a_y4S1, a_y4Sx, a_y4Sxx};
    #pragma unroll
    for (int k = 0; k < 15; ++k) {
        #pragma unroll
        for (int s = 32; s > 0; s >>= 1) v[k] += __shfl_xor(v[k], s);
    }
    int wid = tid >> 6, lane = tid & 63;
    if (lane == 0) {
        #pragma unroll
        for (int k = 0; k < 15; ++k) red[wid][k] = v[k];
    }
    __syncthreads();
    if (tid < 15) {
        float s = red[0][tid] + red[1][tid] + red[2][tid] + red[3][tid];
        int gidx = (tid < 9) ? tid : (9 + (tid - 9)*2 + b);
        atomicAdd(&gacc[gidx], (double)s);
    }
    if (tid < TW) {
        atomicAdd(&dice_i[b*DIM_W + w0 + tid], dsI[tid]);
        atomicAdd(&dice_c[b*DIM_W + w0 + tid], dsC[tid]);
    }
}

__global__ __launch_bounds__(256) void lumen_final(
    const double* __restrict__ gacc,
    const float* __restrict__ dice_i, const float* __restrict__ dice_c,
    const float* __restrict__ gamma_ace, float* __restrict__ out)
{
    __shared__ float red[4];
    int tid = threadIdx.x;
    float s = 0.f;
    for (int i = tid; i < 2*DIM_W; i += 256) {
        float I = dice_i[i], C = dice_c[i];
        s += 1.f - 2.f*I/(C + 1e-6f);
    }
    #pragma unroll
    for (int sh = 32; sh > 0; sh >>= 1) s += __shfl_xor(s, sh);
    if ((tid & 63) == 0) red[tid >> 6] = s;
    __syncthreads();
    if (tid == 0) {
        double dice_sum = (double)red[0] + red[1] + red[2] + red[3];
        double loss_dice = dice_sum / (2.0*DIM_W);
        const double Nb = (double)DIM_D * DIM_H * DIM_W;
        const double Nt = 2.0 * Nb;
        const double eps = 1e-6;
        double loss_ce = gacc[0]/Nt;
        double dl1 = (gacc[1]/Nt) / ((gacc[6]/Nt) + eps);
        double dl2 = (gacc[2]/Nt) / ((gacc[5]/Nt) + eps);
        double dl3 = (gacc[3]/Nt) / (((Nt - gacc[6])/Nt) + eps);
        double dl4 = (gacc[4]/Nt) / (((Nt - gacc[5])/Nt) + eps);
        double loss_dt = dl1 + dl2 + dl3 + dl4;
        double E1n = 0.0, E2n = 0.0;
        for (int bb = 0; bb < 2; ++bb) {
            double S1 = gacc[9+bb],  Sx = gacc[11+bb], Sxx = gacc[13+bb];
            double l1 = (Sx/Nb) / ((S1/Nb) + eps);
            E1n += Sxx - 2.0*l1*Sx + l1*l1*S1;
            double Q1 = gacc[15+bb], Qx = gacc[17+bb], Qxx = gacc[19+bb];
            double l2 = (Qx/Nb) / ((Q1/Nb) + eps);
            E2n += Qxx - 2.0*l2*Qx + l2*l2*Q1;
        }
        double E1 = (E1n/Nt) / (((gacc[9]+gacc[10])/Nt) + eps);
        double E2 = (E2n/Nt) / (((gacc[15]+gacc[16])/Nt) + eps);
        double S  = (gacc[7]/Nt) / ((gacc[8]/Nt) + eps);
        double loss_ace = E1 + E2 + (double)gamma_ace[0]*S;
        out[0] = (float)(loss_ce + loss_dice + 0.1*loss_dt + 0.1*loss_ace);
    }
}

extern "C" void kernel_launch(void* const* d_in, const int* in_sizes, int n_in,
                              void* d_out, int out_size, void* d_ws, size_t ws_size,
                              hipStream_t stream) {
    const float* x_in  = (const float*)d_in[0];
    const float* y_out = (const float*)d_in[1];
    const float* y_tg  = (const float*)d_in[2];
    const float* gamma = (const float*)d_in[4];
    float* out = (float*)d_out;

    double* gacc  = (double*)d_ws;                       // 21 doubles
    float* dice_i = (float*)((char*)d_ws + 512);         // 384 floats
    float* dice_c = (float*)((char*)d_ws + 2048);        // 384 floats

    hipMemsetAsync(d_ws, 0, 4096, stream);

    dim3 grid(DIM_W/TW, DIM_H/TH, 2*(DIM_D/TD));
    lumen_main<<<grid, 256, 0, stream>>>(x_in, y_out, y_tg, gacc, dice_i, dice_c);
    lumen_final<<<1, 256, 0, stream>>>(gacc, dice_i, dice_c, gamma, out);
}